// Round 6
// baseline (322.880 us; speedup 1.0000x reference)
//
#include <hip/hip_runtime.h>
#include <math.h>

// LinearAttention (2nd-order derivative-expanded DeltaNet-like), fp32.
// B=2,H=16,S=2048,D=64; n=2; CHUNK=64 real tokens -> 128 virtual rows/chunk.
// Phase 1: one block per chunk: Gram once + pipelined 1-barrier-per-group
//          forward substitution (I+A)^{-1}[wc|uc] -> d_ws (64 MiB).
// Phase 2: cooperative d-sliced chunk scan, 2 barriers/chunk, redundant
//          in-register reductions, 16 blocks/pair (2 blocks/CU overlap).

namespace {
constexpr int PAIRS = 32;   // B*H
constexpr int SLEN  = 2048;
constexpr int D     = 64;
constexpr int CK    = 64;   // real tokens per chunk
constexpr int CN    = 128;  // virtual rows per chunk
constexpr int NCH   = 32;   // chunks
constexpr int NB2   = 16;   // blocks per pair in phase 2
constexpr int NP    = 5;    // positions per phase-2 block (4 outputs + c=63 replica)

// _stab: nan->0, clip to +-1e4 (also maps +-inf to +-1e4). Clip is load-bearing:
// w*uv products genuinely overflow (1e27*1e33). NaN check must be explicit.
__device__ __forceinline__ float stab1(float x) {
    float y = __builtin_amdgcn_fmed3f(x, -10000.f, 10000.f);  // clamp, 1 inst
    return (x != x) ? 0.f : y;
}

// swizzled float-index into kst: row a, float4 index f4 (0..15), stride 68 floats.
__device__ __forceinline__ int kidx(int a, int f4) {
    return a * 68 + 4 * (f4 ^ ((a >> 2) & 3));
}
} // namespace

// ---------------- Phase 1: Gram matrix + pipelined WY solve ----------------
// grid = PAIRS*NCH (1024), block = 512 (8 waves). LDS ~117KB -> 1 block/CU.
// Main loop: ONE barrier per 8-row group. grp0 (thr 0-127): reduce+fixup+solve(g).
// grp1-3 (thr 128-511): build strip(g+2) + phase-A partials for target g+1 (j<8g).
__global__ __launch_bounds__(512, 1)
void la_phase1(const float* __restrict__ kg, const float* __restrict__ vg,
               const float* __restrict__ bg, float* __restrict__ ws)
{
    __shared__ float Ysh[CN][CN];          // [row][col]; cols 0-63 = w, 64-127 = u
    __shared__ float Gm[65][66];           // Gram of k rows [baseT-1 .. baseT+63]
    __shared__ char  ureg[36864];          // kst[65][68] | scm[3][128][8]+redsh[2][3][8][128]
    __shared__ float bq4[CK], bh[CK];

    float* kstf = (float*)ureg;                                   // 17680 B (prologue only)
    float* scm  = (float*)ureg;                                   // [3][CN][8] = 12288 B
    float (*redsh)[3][8][CN] = (float(*)[3][8][CN])(ureg + 12288);// [2][3][8][128] = 24576 B

    const int blk  = blockIdx.x;
    const int p    = blk >> 5;
    const int nc   = blk & 31;
    const int tid  = threadIdx.x;
    const int baseT = nc * CK;
    const float* kp = kg + (size_t)p * SLEN * D;
    const float* vp = vg + (size_t)p * SLEN * D;
    const float* bp = bg + (size_t)p * SLEN;

    // ---- stage k rows a=0..64  <- k[baseT-1+a] (row 0 zero when baseT==0)
    for (int u = tid; u < 65 * 16; u += 512) {
        int a = u >> 4, f4 = u & 15;
        int src = baseT - 1 + a;
        float4 val = float4{0.f, 0.f, 0.f, 0.f};
        if (src >= 0) val = ((const float4*)(kp + (size_t)src * D))[f4];
        *(float4*)&kstf[kidx(a, f4)] = val;
    }
    if (tid < CK) {
        float bv = bp[baseT + tid];
        bq4[tid] = 0.25f * bv;
        bh[tid]  = 0.5f  * bv;
    }
    __syncthreads();

    // ---- Y init (rows i=2c+s): cols 0-63 = coef*beta*k[t-s] (from kst),
    //      cols 64-127 = coef*beta*v[t-s] (global). coef: s=1 -> +0.5, s=0 -> -0.5.
    for (int u = tid; u < CN * 32; u += 512) {
        int i = u >> 5, f4i = u & 31;
        int ci = i >> 1, si = i & 1;
        float sc = si ? bh[ci] : -bh[ci];
        float4 val = float4{0.f, 0.f, 0.f, 0.f};
        if (f4i < 16) {
            val = *(const float4*)&kstf[kidx(ci - si + 1, f4i)];
        } else {
            int srcT = baseT + ci - si;
            if (srcT >= 0) val = ((const float4*)(vp + (size_t)srcT * D))[f4i - 16];
        }
        val.x *= sc; val.y *= sc; val.z *= sc; val.w *= sc;
        *(float4*)&Ysh[i][f4i * 4] = val;
    }

    // ---- Gram matrix, 4x4 register tiles, lower-triangular tile set + mirror
    for (int tt = tid; tt < 17 * 17; tt += 512) {
        int ta = tt / 17, tb = tt % 17;
        if (tb > ta) continue;
        int a0 = ta * 4, b0 = tb * 4;
        float acc[4][4] = {};
        for (int d4 = 0; d4 < 16; ++d4) {
            float4 av[4], bv[4];
            #pragma unroll
            for (int r = 0; r < 4; ++r) {
                av[r] = *(const float4*)&kstf[kidx(min(a0 + r, 64), d4)];
                bv[r] = *(const float4*)&kstf[kidx(min(b0 + r, 64), d4)];
            }
            #pragma unroll
            for (int r = 0; r < 4; ++r)
                #pragma unroll
                for (int c = 0; c < 4; ++c)
                    acc[r][c] += av[r].x * bv[c].x + av[r].y * bv[c].y
                               + av[r].z * bv[c].z + av[r].w * bv[c].w;
        }
        #pragma unroll
        for (int r = 0; r < 4; ++r)
            #pragma unroll
            for (int c = 0; c < 4; ++c)
                if (a0 + r <= 64 && b0 + c <= 64) {
                    Gm[a0 + r][b0 + c] = acc[r][c];
                    Gm[b0 + c][a0 + r] = acc[r][c];
                }
    }
    __syncthreads();   // kst dead from here; scm/redsh live in ureg

    // ---- prologue: strips for groups 0 (buf0) and 1 (buf1).
    // A[i][j] = sgn*0.25*beta[t_i]*G[a_i][a_j], sgn=+1 iff s_i==s_j; a=(i>>1)-(i&1)+1.
    for (int e = tid; e < 192; e += 512) {
        int gp = (e < 64) ? 0 : 1;
        int ee = e - gp * 64;
        int j = ee >> 3, r = ee & 7;
        int i = 8 * gp + r;
        int ai = (i >> 1) - (i & 1) + 1;
        int aj = (j >> 1) - (j & 1) + 1;
        float sgn = ((i ^ j) & 1) ? -1.f : 1.f;
        scm[(gp * CN + j) * 8 + r] = sgn * bq4[i >> 1] * Gm[ai][aj];
    }
    __syncthreads();

    const int col = tid & 127;
    const int grp = tid >> 7;     // 0..3 (2 waves each; wave-uniform)

    for (int g = 0; g < 16; ++g) {
        const int bufG  = g % 3;          // strip(g): solver
        const int bufG1 = (g + 1) % 3;    // strip(g+1): partial-computers
        const int bufG2 = (g + 2) % 3;    // strip(g+2): being built

        if (grp == 0) {
            // reduce partials (written iter g-1) + fixup j in [8g-8, 8g) + solve
            float acc[8] = {};
            if (g > 0) {
                #pragma unroll
                for (int r = 0; r < 8; ++r)
                    acc[r] = redsh[g & 1][0][r][col] + redsh[g & 1][1][r][col]
                           + redsh[g & 1][2][r][col];
                #pragma unroll
                for (int jj = 0; jj < 8; ++jj) {
                    int j = 8 * g - 8 + jj;
                    float yv = Ysh[j][col];
                    const float4 a03 = *(const float4*)&scm[(bufG * CN + j) * 8];
                    const float4 a47 = *(const float4*)&scm[(bufG * CN + j) * 8 + 4];
                    acc[0] += a03.x * yv; acc[1] += a03.y * yv;
                    acc[2] += a03.z * yv; acc[3] += a03.w * yv;
                    acc[4] += a47.x * yv; acc[5] += a47.y * yv;
                    acc[6] += a47.z * yv; acc[7] += a47.w * yv;
                }
            }
            float yn[8];
            #pragma unroll
            for (int r = 0; r < 8; ++r) {
                float val = Ysh[8 * g + r][col] - acc[r];
                #pragma unroll
                for (int rp = 0; rp < 8; ++rp)
                    if (rp < r) val -= scm[(bufG * CN + 8 * g + rp) * 8 + r] * yn[rp];
                yn[r] = val;
                Ysh[8 * g + r][col] = val;
            }
        } else {
            // build strip(g+2)
            if (g + 2 <= 15) {
                int gb = g + 2, jmax = 8 * gb + 8;
                for (int e = tid - 128; e < 8 * jmax; e += 384) {
                    int j = e >> 3, r = e & 7;
                    int i = 8 * gb + r;
                    int ai = (i >> 1) - (i & 1) + 1;
                    int aj = (j >> 1) - (j & 1) + 1;
                    float sgn = ((i ^ j) & 1) ? -1.f : 1.f;
                    scm[(bufG2 * CN + j) * 8 + r] = sgn * bq4[i >> 1] * Gm[ai][aj];
                }
            }
            // phase-A partials for target g+1 over j < 8g (rows already solved)
            if (g + 1 <= 15) {
                float acc[8] = {};
                for (int j = grp - 1; j < 8 * g; j += 3) {
                    float yv = Ysh[j][col];
                    const float4 a03 = *(const float4*)&scm[(bufG1 * CN + j) * 8];
                    const float4 a47 = *(const float4*)&scm[(bufG1 * CN + j) * 8 + 4];
                    acc[0] += a03.x * yv; acc[1] += a03.y * yv;
                    acc[2] += a03.z * yv; acc[3] += a03.w * yv;
                    acc[4] += a47.x * yv; acc[5] += a47.y * yv;
                    acc[6] += a47.z * yv; acc[7] += a47.w * yv;
                }
                #pragma unroll
                for (int r = 0; r < 8; ++r)
                    redsh[(g + 1) & 1][grp - 1][r][col] = acc[r];
            }
        }
        __syncthreads();
    }

    // ---- writeback [128][128]
    float* gY = ws + (size_t)(p * NCH + nc) * (CN * CN);
    for (int u = tid; u < CN * 32; u += 512) {
        int r = u >> 5, f4 = u & 31;
        *(float4*)&gY[r * CN + f4 * 4] = *(const float4*)&Ysh[r][f4 * 4];
    }
}

// ---------------- Phase 2: cooperative d-sliced chunk scan, 2 barriers/chunk ----
// grid = PAIRS*NB2 (512 blocks -> 2/CU), block = 512 (8 waves).
// Wave w holds h rows [8w,8w+8) (column e=lane) in registers. NP=5 positions:
// P=0..3 -> c = nb*4+P (outputs), P=4 -> c=63 (h-update chain, replicated).
// Schedule per chunk: ROUND1 -> B1 -> {uv0 redundant, ROUND2, stage_write} -> B2
// -> {out-reduce, uv1_63 redundant, h-update in regs} -> (no barrier) next ROUND1.
__global__ __launch_bounds__(512, 4)
void la_phase2(const float* __restrict__ qg, const float* __restrict__ ws,
               float* __restrict__ outg)
{
    __shared__ float WU[2][NP][256];    // staged [w0|u0|w1|u1] per position, dbuf
    __shared__ float Qs[2][NP][64];     // staged raw q rows (0.5 scale at output)
    __shared__ float pR1[8][NP][64];    // kh0 partials (per d-slice wave)
    __shared__ float pKH[8][NP][64];    // kh1 partials
    __shared__ float pOA[8][NP][64];    // oac partials

    const int blk  = blockIdx.x;
    const int p    = blk >> 4, nb = blk & 15;
    const int tid  = threadIdx.x;
    const int w    = tid >> 6, lane = tid & 63;

    const float* qp = qg + (size_t)p * SLEN * D;
    float* op = outg + (size_t)p * SLEN * D;
    const float* wsbase = ws + (size_t)p * NCH * (CN * CN);

    const int cMain = nb * 4 + w;      // valid for w<4 (output positions)

    // staging registers (loaded at chunk top, written to LDS before B2)
    float4 wuR = float4{0.f, 0.f, 0.f, 0.f};
    float  qR  = 0.f;

    auto stage_load = [&](int nc) {
        const float* gY = wsbase + (size_t)nc * (CN * CN);
        if (w < 4) {
            wuR = *(const float4*)(gY + (size_t)(2 * cMain) * CN + lane * 4);
            int t = nc * CK + cMain;
            qR = qp[(size_t)((t > 0) ? t - 1 : 0) * D + lane];
        } else if (w == 4) {
            wuR = *(const float4*)(gY + (size_t)126 * CN + lane * 4);
            qR = qp[(size_t)(nc * CK + 62) * D + lane];
        }
    };
    auto stage_write = [&](int buf) {
        if (w < NP) {
            *(float4*)&WU[buf][w][lane * 4] = wuR;
            Qs[buf][w][lane] = qR;
        }
    };

    float hs[8];
    #pragma unroll
    for (int j = 0; j < 8; ++j) hs[j] = 0.f;

    stage_load(0);
    stage_write(0);
    __syncthreads();

    for (int nc = 0; nc < NCH; ++nc) {
        const int buf = nc & 1;
        if (nc + 1 < NCH) stage_load(nc + 1);   // issue early; LDS-write before B2

        // ---- ROUND 1: kh0 partials over d-slice [8w,8w+8)
        #pragma unroll
        for (int P = 0; P < NP; ++P) {
            float4 a = *(const float4*)&WU[buf][P][8 * w];
            float4 b = *(const float4*)&WU[buf][P][8 * w + 4];
            pR1[w][P][lane] =
                  ((a.x * hs[0] + a.y * hs[1]) + (a.z * hs[2] + a.w * hs[3]))
                + ((b.x * hs[4] + b.y * hs[5]) + (b.z * hs[6] + b.w * hs[7]));
        }
        __syncthreads();   // B1

        // ---- uv0 for all positions, redundantly per wave (registers)
        float uv0r[NP];
        #pragma unroll
        for (int P = 0; P < NP; ++P) {
            float s = 0.f;
            #pragma unroll
            for (int wv = 0; wv < 8; ++wv) s += pR1[wv][P][lane];
            uv0r[P] = WU[buf][P][64 + lane] - s;
        }

        // ---- ROUND 2: st1 = stab(h + w0*uv0); kh1/oac partials over d-slice
        #pragma unroll
        for (int P = 0; P < NP; ++P) {
            float uv0 = uv0r[P];
            float4 w0a = *(const float4*)&WU[buf][P][8 * w];
            float4 w0b = *(const float4*)&WU[buf][P][8 * w + 4];
            float4 w1a = *(const float4*)&WU[buf][P][128 + 8 * w];
            float4 w1b = *(const float4*)&WU[buf][P][128 + 8 * w + 4];
            float4 qa  = *(const float4*)&Qs[buf][P][8 * w];
            float4 qb  = *(const float4*)&Qs[buf][P][8 * w + 4];
            float st0 = stab1(hs[0] + w0a.x * uv0);
            float st1 = stab1(hs[1] + w0a.y * uv0);
            float st2 = stab1(hs[2] + w0a.z * uv0);
            float st3 = stab1(hs[3] + w0a.w * uv0);
            float st4 = stab1(hs[4] + w0b.x * uv0);
            float st5 = stab1(hs[5] + w0b.y * uv0);
            float st6 = stab1(hs[6] + w0b.z * uv0);
            float st7 = stab1(hs[7] + w0b.w * uv0);
            pKH[w][P][lane] =
                  ((w1a.x * st0 + w1a.y * st1) + (w1a.z * st2 + w1a.w * st3))
                + ((w1b.x * st4 + w1b.y * st5) + (w1b.z * st6 + w1b.w * st7));
            pOA[w][P][lane] =
                  ((qa.x * st0 + qa.y * st1) + (qa.z * st2 + qa.w * st3))
                + ((qb.x * st4 + qb.y * st5) + (qb.z * st6 + qb.w * st7));
        }
        stage_write(buf ^ 1);
        __syncthreads();   // B2

        // ---- outputs for P=0..3 (waves 0-3)
        if (w < 4) {
            float skh = 0.f, soa = 0.f;
            #pragma unroll
            for (int wv = 0; wv < 8; ++wv) {
                skh += pKH[wv][w][lane];
                soa += pOA[wv][w][lane];
            }
            float uv1 = WU[buf][w][192 + lane] - skh;
            int t = nc * CK + cMain;
            float outv = 0.5f * (Qs[buf][w][lane] * uv1 + soa);
            op[(size_t)t * D + lane] = (t > 0) ? outv : 0.f;
        }

        // ---- uv1 at c=63, redundantly per wave
        float skh4 = 0.f;
        #pragma unroll
        for (int wv = 0; wv < 8; ++wv) skh4 += pKH[wv][4][lane];
        const float uv1l = WU[buf][4][192 + lane] - skh4;
        const float uv0l = uv0r[4];

        // ---- H-UPDATE (in registers): rows [8w,8w+8), column e=lane.
        // state2 = stab(stab(h + w0_63 x uv0_63) + w1_63 x uv1_63);
        // h' = 0.25*x*y*(1+tanh(z)), y = 2x/(rownorm+1e-6). Norm over e -> butterfly.
        {
            float4 w0a = *(const float4*)&WU[buf][4][8 * w];
            float4 w0b = *(const float4*)&WU[buf][4][8 * w + 4];
            float4 w1a = *(const float4*)&WU[buf][4][128 + 8 * w];
            float4 w1b = *(const float4*)&WU[buf][4][128 + 8 * w + 4];
            float st2v[8], ss[8];
            st2v[0] = stab1(stab1(hs[0] + w0a.x * uv0l) + w1a.x * uv1l);
            st2v[1] = stab1(stab1(hs[1] + w0a.y * uv0l) + w1a.y * uv1l);
            st2v[2] = stab1(stab1(hs[2] + w0a.z * uv0l) + w1a.z * uv1l);
            st2v[3] = stab1(stab1(hs[3] + w0a.w * uv0l) + w1a.w * uv1l);
            st2v[4] = stab1(stab1(hs[4] + w0b.x * uv0l) + w1b.x * uv1l);
            st2v[5] = stab1(stab1(hs[5] + w0b.y * uv0l) + w1b.y * uv1l);
            st2v[6] = stab1(stab1(hs[6] + w0b.z * uv0l) + w1b.z * uv1l);
            st2v[7] = stab1(stab1(hs[7] + w0b.w * uv0l) + w1b.w * uv1l);
            #pragma unroll
            for (int j = 0; j < 8; ++j) ss[j] = st2v[j] * st2v[j];
            #pragma unroll
            for (int msk = 1; msk < 64; msk <<= 1) {
                #pragma unroll
                for (int j = 0; j < 8; ++j) ss[j] += __shfl_xor(ss[j], msk);
            }
            #pragma unroll
            for (int j = 0; j < 8; ++j) {
                float xn = __builtin_amdgcn_sqrtf(ss[j]) + 1e-6f;
                float y  = 2.f * st2v[j] * __builtin_amdgcn_rcpf(xn);  // in [-2,2]
                float y2 = y * y;
                float e  = __builtin_amdgcn_exp2f(y * (2.3022078f + 0.1029432f * y2));
                float th = (e - 1.f) * __builtin_amdgcn_rcpf(e + 1.f);
                hs[j] = 0.25f * st2v[j] * y * (1.f + th);
            }
        }
        // no barrier: next ROUND1 writes pR1 (last read pre-B2) and reads
        // WU/Qs[buf^1] (written pre-B2); pKH/pOA rewrites happen after next B1.
    }
}

extern "C" void kernel_launch(void* const* d_in, const int* in_sizes, int n_in,
                              void* d_out, int out_size, void* d_ws, size_t ws_size,
                              hipStream_t stream)
{
    (void)in_sizes; (void)n_in; (void)out_size; (void)ws_size;
    const float* q    = (const float*)d_in[0];
    const float* k    = (const float*)d_in[1];
    const float* v    = (const float*)d_in[2];
    const float* beta = (const float*)d_in[3];
    float* ws  = (float*)d_ws;    // 32*32*128*128*4 = 64 MiB
    float* out = (float*)d_out;

    la_phase1<<<PAIRS * NCH, 512, 0, stream>>>(k, v, beta, ws);
    la_phase2<<<PAIRS * NB2, 512, 0, stream>>>(q, ws, out);
}

// Round 7
// 275.069 us; speedup vs baseline: 1.1738x; 1.1738x over previous
//
#include <hip/hip_runtime.h>
#include <math.h>

// LinearAttention (2nd-order derivative-expanded DeltaNet-like), fp32.
// B=2,H=16,S=2048,D=64; n=2; CHUNK=64 real tokens -> 128 virtual rows/chunk.
// Phase 1: one block per chunk: Gram once + pipelined 1-barrier-per-group
//          forward substitution (I+A)^{-1}[wc|uc] -> d_ws (64 MiB).
// Phase 2: cooperative d-sliced chunk scan; h in LDS; designated reductions;
//          row-mapped h-update (3-shfl norm); 16 blocks/pair, 2 blocks/CU.

namespace {
constexpr int PAIRS = 32;   // B*H
constexpr int SLEN  = 2048;
constexpr int D     = 64;
constexpr int CK    = 64;   // real tokens per chunk
constexpr int CN    = 128;  // virtual rows per chunk
constexpr int NCH   = 32;   // chunks
constexpr int NB2   = 16;   // blocks per pair in phase 2
constexpr int NP    = 5;    // positions per phase-2 block (4 outputs + c=63 replica)

// _stab: nan->0, clip to +-1e4 (also maps +-inf to +-1e4). Clip is load-bearing:
// w*uv products genuinely overflow (1e27*1e33). NaN check must be explicit.
__device__ __forceinline__ float stab1(float x) {
    float y = __builtin_amdgcn_fmed3f(x, -10000.f, 10000.f);  // clamp, 1 inst
    return (x != x) ? 0.f : y;
}

// swizzled float-index into kst: row a, float4 index f4 (0..15), stride 68 floats.
__device__ __forceinline__ int kidx(int a, int f4) {
    return a * 68 + 4 * (f4 ^ ((a >> 2) & 3));
}
} // namespace

// ---------------- Phase 1: Gram matrix + pipelined WY solve ----------------
// grid = PAIRS*NCH (1024), block = 512 (8 waves). LDS ~117KB -> 1 block/CU.
// Main loop: ONE barrier per 8-row group. grp0 (thr 0-127): reduce+fixup+solve(g).
// grp1-3 (thr 128-511): build strip(g+2) + phase-A partials for target g+1 (j<8g).
__global__ __launch_bounds__(512, 1)
void la_phase1(const float* __restrict__ kg, const float* __restrict__ vg,
               const float* __restrict__ bg, float* __restrict__ ws)
{
    __shared__ float Ysh[CN][CN];          // [row][col]; cols 0-63 = w, 64-127 = u
    __shared__ float Gm[65][66];           // Gram of k rows [baseT-1 .. baseT+63]
    __shared__ char  ureg[36864];          // kst[65][68] | scm[3][128][8]+redsh[2][3][8][128]
    __shared__ float bq4[CK], bh[CK];

    float* kstf = (float*)ureg;                                   // 17680 B (prologue only)
    float* scm  = (float*)ureg;                                   // [3][CN][8] = 12288 B
    float (*redsh)[3][8][CN] = (float(*)[3][8][CN])(ureg + 12288);// [2][3][8][128] = 24576 B

    const int blk  = blockIdx.x;
    const int p    = blk >> 5;
    const int nc   = blk & 31;
    const int tid  = threadIdx.x;
    const int baseT = nc * CK;
    const float* kp = kg + (size_t)p * SLEN * D;
    const float* vp = vg + (size_t)p * SLEN * D;
    const float* bp = bg + (size_t)p * SLEN;

    // ---- stage k rows a=0..64  <- k[baseT-1+a] (row 0 zero when baseT==0)
    for (int u = tid; u < 65 * 16; u += 512) {
        int a = u >> 4, f4 = u & 15;
        int src = baseT - 1 + a;
        float4 val = float4{0.f, 0.f, 0.f, 0.f};
        if (src >= 0) val = ((const float4*)(kp + (size_t)src * D))[f4];
        *(float4*)&kstf[kidx(a, f4)] = val;
    }
    if (tid < CK) {
        float bv = bp[baseT + tid];
        bq4[tid] = 0.25f * bv;
        bh[tid]  = 0.5f  * bv;
    }
    __syncthreads();

    // ---- Y init (rows i=2c+s): cols 0-63 = coef*beta*k[t-s] (from kst),
    //      cols 64-127 = coef*beta*v[t-s] (global). coef: s=1 -> +0.5, s=0 -> -0.5.
    for (int u = tid; u < CN * 32; u += 512) {
        int i = u >> 5, f4i = u & 31;
        int ci = i >> 1, si = i & 1;
        float sc = si ? bh[ci] : -bh[ci];
        float4 val = float4{0.f, 0.f, 0.f, 0.f};
        if (f4i < 16) {
            val = *(const float4*)&kstf[kidx(ci - si + 1, f4i)];
        } else {
            int srcT = baseT + ci - si;
            if (srcT >= 0) val = ((const float4*)(vp + (size_t)srcT * D))[f4i - 16];
        }
        val.x *= sc; val.y *= sc; val.z *= sc; val.w *= sc;
        *(float4*)&Ysh[i][f4i * 4] = val;
    }

    // ---- Gram matrix, 4x4 register tiles, lower-triangular tile set + mirror
    for (int tt = tid; tt < 17 * 17; tt += 512) {
        int ta = tt / 17, tb = tt % 17;
        if (tb > ta) continue;
        int a0 = ta * 4, b0 = tb * 4;
        float acc[4][4] = {};
        for (int d4 = 0; d4 < 16; ++d4) {
            float4 av[4], bv[4];
            #pragma unroll
            for (int r = 0; r < 4; ++r) {
                av[r] = *(const float4*)&kstf[kidx(min(a0 + r, 64), d4)];
                bv[r] = *(const float4*)&kstf[kidx(min(b0 + r, 64), d4)];
            }
            #pragma unroll
            for (int r = 0; r < 4; ++r)
                #pragma unroll
                for (int c = 0; c < 4; ++c)
                    acc[r][c] += av[r].x * bv[c].x + av[r].y * bv[c].y
                               + av[r].z * bv[c].z + av[r].w * bv[c].w;
        }
        #pragma unroll
        for (int r = 0; r < 4; ++r)
            #pragma unroll
            for (int c = 0; c < 4; ++c)
                if (a0 + r <= 64 && b0 + c <= 64) {
                    Gm[a0 + r][b0 + c] = acc[r][c];
                    Gm[b0 + c][a0 + r] = acc[r][c];
                }
    }
    __syncthreads();   // kst dead from here; scm/redsh live in ureg

    // ---- prologue: strips for groups 0 (buf0) and 1 (buf1).
    // A[i][j] = sgn*0.25*beta[t_i]*G[a_i][a_j], sgn=+1 iff s_i==s_j; a=(i>>1)-(i&1)+1.
    for (int e = tid; e < 192; e += 512) {
        int gp = (e < 64) ? 0 : 1;
        int ee = e - gp * 64;
        int j = ee >> 3, r = ee & 7;
        int i = 8 * gp + r;
        int ai = (i >> 1) - (i & 1) + 1;
        int aj = (j >> 1) - (j & 1) + 1;
        float sgn = ((i ^ j) & 1) ? -1.f : 1.f;
        scm[(gp * CN + j) * 8 + r] = sgn * bq4[i >> 1] * Gm[ai][aj];
    }
    __syncthreads();

    const int col = tid & 127;
    const int grp = tid >> 7;     // 0..3 (2 waves each; wave-uniform)

    for (int g = 0; g < 16; ++g) {
        const int bufG  = g % 3;          // strip(g): solver
        const int bufG1 = (g + 1) % 3;    // strip(g+1): partial-computers
        const int bufG2 = (g + 2) % 3;    // strip(g+2): being built

        if (grp == 0) {
            // reduce partials (written iter g-1) + fixup j in [8g-8, 8g) + solve
            float acc[8] = {};
            if (g > 0) {
                #pragma unroll
                for (int r = 0; r < 8; ++r)
                    acc[r] = redsh[g & 1][0][r][col] + redsh[g & 1][1][r][col]
                           + redsh[g & 1][2][r][col];
                #pragma unroll
                for (int jj = 0; jj < 8; ++jj) {
                    int j = 8 * g - 8 + jj;
                    float yv = Ysh[j][col];
                    const float4 a03 = *(const float4*)&scm[(bufG * CN + j) * 8];
                    const float4 a47 = *(const float4*)&scm[(bufG * CN + j) * 8 + 4];
                    acc[0] += a03.x * yv; acc[1] += a03.y * yv;
                    acc[2] += a03.z * yv; acc[3] += a03.w * yv;
                    acc[4] += a47.x * yv; acc[5] += a47.y * yv;
                    acc[6] += a47.z * yv; acc[7] += a47.w * yv;
                }
            }
            float yn[8];
            #pragma unroll
            for (int r = 0; r < 8; ++r) {
                float val = Ysh[8 * g + r][col] - acc[r];
                #pragma unroll
                for (int rp = 0; rp < 8; ++rp)
                    if (rp < r) val -= scm[(bufG * CN + 8 * g + rp) * 8 + r] * yn[rp];
                yn[r] = val;
                Ysh[8 * g + r][col] = val;
            }
        } else {
            // build strip(g+2)
            if (g + 2 <= 15) {
                int gb = g + 2, jmax = 8 * gb + 8;
                for (int e = tid - 128; e < 8 * jmax; e += 384) {
                    int j = e >> 3, r = e & 7;
                    int i = 8 * gb + r;
                    int ai = (i >> 1) - (i & 1) + 1;
                    int aj = (j >> 1) - (j & 1) + 1;
                    float sgn = ((i ^ j) & 1) ? -1.f : 1.f;
                    scm[(bufG2 * CN + j) * 8 + r] = sgn * bq4[i >> 1] * Gm[ai][aj];
                }
            }
            // phase-A partials for target g+1 over j < 8g (rows already solved)
            if (g + 1 <= 15) {
                float acc[8] = {};
                for (int j = grp - 1; j < 8 * g; j += 3) {
                    float yv = Ysh[j][col];
                    const float4 a03 = *(const float4*)&scm[(bufG1 * CN + j) * 8];
                    const float4 a47 = *(const float4*)&scm[(bufG1 * CN + j) * 8 + 4];
                    acc[0] += a03.x * yv; acc[1] += a03.y * yv;
                    acc[2] += a03.z * yv; acc[3] += a03.w * yv;
                    acc[4] += a47.x * yv; acc[5] += a47.y * yv;
                    acc[6] += a47.z * yv; acc[7] += a47.w * yv;
                }
                #pragma unroll
                for (int r = 0; r < 8; ++r)
                    redsh[(g + 1) & 1][grp - 1][r][col] = acc[r];
            }
        }
        __syncthreads();
    }

    // ---- writeback [128][128]
    float* gY = ws + (size_t)(p * NCH + nc) * (CN * CN);
    for (int u = tid; u < CN * 32; u += 512) {
        int r = u >> 5, f4 = u & 31;
        *(float4*)&gY[r * CN + f4 * 4] = *(const float4*)&Ysh[r][f4 * 4];
    }
}

// ---------------- Phase 2: cooperative d-sliced chunk scan ----------------
// grid = PAIRS*NB2 (512 blocks -> 2/CU), block = 512 (8 waves).
// Wave w contributes partials for d-slice [8w,8w+8) (column e=lane); h lives in
// LDS hsh[64][67]. NP=5 positions: P=0..3 -> c = nb*4+P (outputs), P=4 -> c=63.
// Schedule: R1 -> B1 -> UV0 designated -> B2 -> R2 + stage_write -> B3 ->
//           out/UV1 designated -> B4 -> row-mapped h-update -> B5.
__global__ __launch_bounds__(512, 4)
void la_phase2(const float* __restrict__ qg, const float* __restrict__ ws,
               float* __restrict__ outg)
{
    __shared__ float WU[2][NP][256];    // staged [w0|u0|w1|u1] per position, dbuf
    __shared__ float Qs[2][NP][64];     // staged raw q rows (0.5 scale at output)
    __shared__ float pR1[8][NP][64];    // kh0 partials (per d-slice wave)
    __shared__ float pKH[8][NP][64];    // kh1 partials
    __shared__ float pOA[8][NP][64];    // oac partials
    __shared__ float UV0[NP][64];       // uv0 per position
    __shared__ float UV1r[64];          // uv1 at c=63
    __shared__ float hsh[64][67];       // h[d][e]; 67%32=3 -> row & col modes conflict-free

    const int blk  = blockIdx.x;
    const int p    = blk >> 4, nb = blk & 15;
    const int tid  = threadIdx.x;
    const int w    = tid >> 6, lane = tid & 63;
    const int hd   = tid >> 3;          // h-update: row 0..63
    const int he0  = (tid & 7) * 8;     // h-update: 8 columns [he0, he0+8)

    const float* qp = qg + (size_t)p * SLEN * D;
    float* op = outg + (size_t)p * SLEN * D;
    const float* wsbase = ws + (size_t)p * NCH * (CN * CN);

    const int cMain = nb * 4 + w;      // valid for w<4 (output positions)

    float4 wuR = float4{0.f, 0.f, 0.f, 0.f};
    float  qR  = 0.f;

    auto stage_load = [&](int nc) {
        const float* gY = wsbase + (size_t)nc * (CN * CN);
        if (w < 4) {
            wuR = *(const float4*)(gY + (size_t)(2 * cMain) * CN + lane * 4);
            int t = nc * CK + cMain;
            qR = qp[(size_t)((t > 0) ? t - 1 : 0) * D + lane];
        } else if (w == 4) {
            wuR = *(const float4*)(gY + (size_t)126 * CN + lane * 4);
            qR = qp[(size_t)(nc * CK + 62) * D + lane];
        }
    };
    auto stage_write = [&](int buf) {
        if (w < NP) {
            *(float4*)&WU[buf][w][lane * 4] = wuR;
            Qs[buf][w][lane] = qR;
        }
    };

    for (int idx = tid; idx < 64 * 67; idx += 512) (&hsh[0][0])[idx] = 0.f;
    stage_load(0);
    stage_write(0);
    __syncthreads();

    for (int nc = 0; nc < NCH; ++nc) {
        const int buf = nc & 1;

        // h d-slice for this wave (column e=lane), fresh after previous B5
        float hs[8];
        #pragma unroll
        for (int j = 0; j < 8; ++j) hs[j] = hsh[8 * w + j][lane];

        if (nc + 1 < NCH) stage_load(nc + 1);   // issue early; LDS-write before B3

        // ---- ROUND 1: kh0 partials over d-slice [8w,8w+8)
        #pragma unroll
        for (int P = 0; P < NP; ++P) {
            float4 a = *(const float4*)&WU[buf][P][8 * w];
            float4 b = *(const float4*)&WU[buf][P][8 * w + 4];
            pR1[w][P][lane] =
                  ((a.x * hs[0] + a.y * hs[1]) + (a.z * hs[2] + a.w * hs[3]))
                + ((b.x * hs[4] + b.y * hs[5]) + (b.z * hs[6] + b.w * hs[7]));
        }
        __syncthreads();   // B1

        // ---- UV0 designated: wave w (< NP) reduces position P=w
        if (w < NP) {
            float s = 0.f;
            #pragma unroll
            for (int wv = 0; wv < 8; ++wv) s += pR1[wv][w][lane];
            UV0[w][lane] = WU[buf][w][64 + lane] - s;
        }
        __syncthreads();   // B2

        // ---- ROUND 2: st1 = stab(h + w0*uv0); kh1/oac partials over d-slice
        #pragma unroll
        for (int P = 0; P < NP; ++P) {
            float uv0 = UV0[P][lane];
            float4 w0a = *(const float4*)&WU[buf][P][8 * w];
            float4 w0b = *(const float4*)&WU[buf][P][8 * w + 4];
            float4 w1a = *(const float4*)&WU[buf][P][128 + 8 * w];
            float4 w1b = *(const float4*)&WU[buf][P][128 + 8 * w + 4];
            float4 qa  = *(const float4*)&Qs[buf][P][8 * w];
            float4 qb  = *(const float4*)&Qs[buf][P][8 * w + 4];
            float st0 = stab1(hs[0] + w0a.x * uv0);
            float st1 = stab1(hs[1] + w0a.y * uv0);
            float st2 = stab1(hs[2] + w0a.z * uv0);
            float st3 = stab1(hs[3] + w0a.w * uv0);
            float st4 = stab1(hs[4] + w0b.x * uv0);
            float st5 = stab1(hs[5] + w0b.y * uv0);
            float st6 = stab1(hs[6] + w0b.z * uv0);
            float st7 = stab1(hs[7] + w0b.w * uv0);
            pKH[w][P][lane] =
                  ((w1a.x * st0 + w1a.y * st1) + (w1a.z * st2 + w1a.w * st3))
                + ((w1b.x * st4 + w1b.y * st5) + (w1b.z * st6 + w1b.w * st7));
            pOA[w][P][lane] =
                  ((qa.x * st0 + qa.y * st1) + (qa.z * st2 + qa.w * st3))
                + ((qb.x * st4 + qb.y * st5) + (qb.z * st6 + qb.w * st7));
        }
        stage_write(buf ^ 1);
        __syncthreads();   // B3

        // ---- designated: outputs (waves 0-3) and UV1r (wave 4)
        if (w < 4) {
            float skh = 0.f, soa = 0.f;
            #pragma unroll
            for (int wv = 0; wv < 8; ++wv) {
                skh += pKH[wv][w][lane];
                soa += pOA[wv][w][lane];
            }
            float uv1 = WU[buf][w][192 + lane] - skh;
            int t = nc * CK + cMain;
            float outv = 0.5f * (Qs[buf][w][lane] * uv1 + soa);
            op[(size_t)t * D + lane] = (t > 0) ? outv : 0.f;
        } else if (w == 4) {
            float skh = 0.f;
            #pragma unroll
            for (int wv = 0; wv < 8; ++wv) skh += pKH[wv][4][lane];
            UV1r[lane] = WU[buf][4][192 + lane] - skh;
        }
        __syncthreads();   // B4

        // ---- H-UPDATE, row-mapped: thread = (row hd, cols he0..he0+7).
        // state2 = stab(stab(h + w0_63 x uv0_63) + w1_63 x uv1_63);
        // h' = 0.25*x*y*(1+tanh(z)), y = 2x/(rownorm+1e-6); norm over e ->
        // 8 local squares + 3-shfl reduce (threads sharing hd differ in low 3 tid bits).
        {
            float w0d = WU[buf][4][hd];
            float w1d = WU[buf][4][128 + hd];
            float st2v[8];
            float ssum = 0.f;
            #pragma unroll
            for (int j = 0; j < 8; ++j) {
                float st1 = stab1(hsh[hd][he0 + j] + w0d * UV0[4][he0 + j]);
                float st2 = stab1(st1 + w1d * UV1r[he0 + j]);
                st2v[j] = st2;
                ssum += st2 * st2;
            }
            ssum += __shfl_xor(ssum, 1);
            ssum += __shfl_xor(ssum, 2);
            ssum += __shfl_xor(ssum, 4);
            float xn = __builtin_amdgcn_sqrtf(ssum) + 1e-6f;
            float s2 = 2.f * __builtin_amdgcn_rcpf(xn);
            #pragma unroll
            for (int j = 0; j < 8; ++j) {
                float x  = st2v[j];
                float y  = x * s2;                       // in [-2, 2]
                float y2 = y * y;
                float e  = __builtin_amdgcn_exp2f(y * (2.3022078f + 0.1029432f * y2));
                float th = (e - 1.f) * __builtin_amdgcn_rcpf(e + 1.f);
                hsh[hd][he0 + j] = 0.25f * x * y * (1.f + th);
            }
        }
        __syncthreads();   // B5 (h visible to next chunk's column loads)
    }
}

extern "C" void kernel_launch(void* const* d_in, const int* in_sizes, int n_in,
                              void* d_out, int out_size, void* d_ws, size_t ws_size,
                              hipStream_t stream)
{
    (void)in_sizes; (void)n_in; (void)out_size; (void)ws_size;
    const float* q    = (const float*)d_in[0];
    const float* k    = (const float*)d_in[1];
    const float* v    = (const float*)d_in[2];
    const float* beta = (const float*)d_in[3];
    float* ws  = (float*)d_ws;    // 32*32*128*128*4 = 64 MiB
    float* out = (float*)d_out;

    la_phase1<<<PAIRS * NCH, 512, 0, stream>>>(k, v, beta, ws);
    la_phase2<<<PAIRS * NB2, 512, 0, stream>>>(q, ws, out);
}